// Round 1
// baseline (139.036 us; speedup 1.0000x reference)
//
#include <hip/hip_runtime.h>
#include <math.h>

// CapsuleLayer dynamic routing, fused. R7: MB=1, x read direct from L2
// (no LDS staging), priors in registers (36 VGPR), LDS only for
// logits+reductions (~5 KB). waves_per_eu(6) -> VGPR cap ~80 -> 3 blocks/CU
// = 6 waves/EU (75% occupancy) vs R6's LDS-pinned 4 waves/EU (38.6% meas).
// R6 diagnosis: latency-bound, all pipes <=25%; x-staging spent 73.7 KB LDS
// to save loads that the coalescer broadcasts for free (4 og lanes share
// each x address within one instruction). Cost: W L2 traffic 755 MB -> 1.5 GB
// (L2 was at ~25% util, has headroom).

#define NBATCH 256
#define NC 10
#define NR 1152
#define IC 8
#define OC 16
#define NITER 3
#define T 512
#define RPT 9    // NR / 128 r-values per thread

__device__ __forceinline__ float wave_sum(float v) {
#pragma unroll
    for (int m = 1; m <= 32; m <<= 1) v += __shfl_xor(v, m, 64);
    return v;
}
__device__ __forceinline__ float wave_max(float v) {
#pragma unroll
    for (int m = 1; m <= 32; m <<= 1) v = fmaxf(v, __shfl_xor(v, m, 64));
    return v;
}

__global__ __launch_bounds__(T)
__attribute__((amdgpu_waves_per_eu(6)))   // >=6 waves/EU -> VGPR budget ~80
void caps_route(
    const float* __restrict__ x,   // [B, NR, IC]
    const float* __restrict__ W,   // [NC, NR, IC, OC]
    float* __restrict__ out)       // [B, NC, OC]
{
    __shared__ float logit[NR];    // 4608 B
    __shared__ float red[128];     // 8 waves x 16 outputs
    __shared__ float vout[OC];

    const int t    = threadIdx.x;
    const int og   = t & 3;        // o-quad (o = og*4+j)
    const int rr   = t >> 2;       // 0..127
    const int lane = t & 63;
    const int wid  = t >> 6;       // 0..7

    const int c = blockIdx.x >> 8;     // c-major: 256 consecutive blocks share W[c]
    const int b = blockIdx.x & 255;

    // ---------------- Phase A: pri[p] for r=rr+128p, o-quad og --------------
    float4 pri[RPT];
    const float4* __restrict__ wb = (const float4*)(W + (size_t)c * (NR * IC * OC));
    const float4* __restrict__ xg = (const float4*)(x + (size_t)b * (NR * IC));
#pragma unroll
    for (int p = 0; p < RPT; ++p) {
        const int r = rr + (p << 7);
        float4 xa = xg[2 * r], xc = xg[2 * r + 1];   // broadcast-coalesced (4 og lanes/addr)
        float xv[8] = {xa.x, xa.y, xa.z, xa.w, xc.x, xc.y, xc.z, xc.w};
        const float4* wp = wb + (size_t)r * 32 + og; // float4 idx (r*8+i)*4+og
        float4 a = make_float4(0.f, 0.f, 0.f, 0.f);
#pragma unroll
        for (int i = 0; i < 8; ++i) {
            float4 w = wp[i * 4];
            a.x = fmaf(xv[i], w.x, a.x);
            a.y = fmaf(xv[i], w.y, a.y);
            a.z = fmaf(xv[i], w.z, a.z);
            a.w = fmaf(xv[i], w.w, a.w);
        }
        pri[p] = a;
    }

    // ---------------- Phase B: 3 routing iterations -------------------------
    for (int it = 0; it < NITER; ++it) {
        const bool uni = (it == 0);  // softmax of zeros = uniform
        float m = 0.f, invd = 0.f;
        if (!uni) {
            float lm = -3.4e38f;
#pragma unroll
            for (int k = 0; k < 3; ++k) {
                int r = t + (k << 9);
                if (r < NR) lm = fmaxf(lm, logit[r]);
            }
            lm = wave_max(lm);
            if (lane == 0) red[wid] = lm;
            __syncthreads();
            m = red[0];
#pragma unroll
            for (int w = 1; w < 8; ++w) m = fmaxf(m, red[w]);
            float ls = 0.f;
#pragma unroll
            for (int k = 0; k < 3; ++k) {
                int r = t + (k << 9);
                if (r < NR) ls += __expf(logit[r] - m);
            }
            ls = wave_sum(ls);
            __syncthreads();             // m reads of red done before rewrite
            if (lane == 0) red[wid] = ls;
            __syncthreads();
            float d = red[0];
#pragma unroll
            for (int w = 1; w < 8; ++w) d += red[w];
            invd = 1.f / d;
        }

        // s[o] partials
        float4 s = make_float4(0.f, 0.f, 0.f, 0.f);
#pragma unroll
        for (int k = 0; k < RPT; ++k) {
            float w = 1.0f;
            if (!uni) w = __expf(logit[rr + (k << 7)] - m);
            s.x = fmaf(w, pri[k].x, s.x);
            s.y = fmaf(w, pri[k].y, s.y);
            s.z = fmaf(w, pri[k].z, s.z);
            s.w = fmaf(w, pri[k].w, s.w);
        }
        // reduce over the 16 rr slots (same og) within each wave
#pragma unroll
        for (int msk = 4; msk <= 32; msk <<= 1) {
            s.x += __shfl_xor(s.x, msk, 64);
            s.y += __shfl_xor(s.y, msk, 64);
            s.z += __shfl_xor(s.z, msk, 64);
            s.w += __shfl_xor(s.w, msk, 64);
        }
        __syncthreads();                 // stats reads of red done
        if (lane < 4) ((float4*)red)[wid * 4 + og] = s;  // red[wid*16+o]
        __syncthreads();

        if (t < OC) {
            float sv = 0.f;
#pragma unroll
            for (int w = 0; w < 8; ++w) sv += red[w * 16 + t];
            sv *= uni ? (1.0f / 1152.0f) : invd;
            float sq = sv * sv;
#pragma unroll
            for (int msk = 1; msk <= 8; msk <<= 1) sq += __shfl_xor(sq, msk, 64);
            float v = sv * (sqrtf(sq) / (1.0f + sq)); // squash
            if (it == NITER - 1) out[((size_t)b * NC + c) * OC + t] = v;
            else vout[t] = v;
        }
        __syncthreads();

        if (it < NITER - 1) {
            // logit[r] += sum_o pri[r][o]*v[o]
            float4 v4 = ((const float4*)vout)[og];
#pragma unroll
            for (int k = 0; k < RPT; ++k) {
                const int r = rr + (k << 7);
                float d = pri[k].x * v4.x + pri[k].y * v4.y +
                          pri[k].z * v4.z + pri[k].w * v4.w;
                d += __shfl_xor(d, 1, 64);   // sum the 4 og partials
                d += __shfl_xor(d, 2, 64);
                if (og == 0) {
                    if (it == 0) logit[r] = d;
                    else         logit[r] += d;
                }
            }
            __syncthreads();
        }
    }
}

extern "C" void kernel_launch(void* const* d_in, const int* in_sizes, int n_in,
                              void* d_out, int out_size, void* d_ws, size_t ws_size,
                              hipStream_t stream) {
    const float* x = (const float*)d_in[0];
    const float* W = (const float*)d_in[1];
    float* out = (float*)d_out;
    caps_route<<<dim3(NC * NBATCH), dim3(T), 0, stream>>>(x, W, out);
}